// Round 2
// baseline (182.266 us; speedup 1.0000x reference)
//
#include <hip/hip_runtime.h>

#define N 1024
#define D 2048
#define P 8
#define F 9
#define KTOT (F * D)          // 18432
#define BM 128                // tile M = N = 128
#define BKT 32                // K per step (16x16x32 MFMA)
#define MARGIN 0.3f

typedef float f32x4 __attribute__((ext_vector_type(4)));
typedef short s16x8 __attribute__((ext_vector_type(8)));

#define GLOBAL_AS __attribute__((address_space(1)))
#define LDS_AS __attribute__((address_space(3)))

__device__ __forceinline__ const float* feat_row(const float* __restrict__ g,
                                                 const float* __restrict__ p,
                                                 int i, int f) {
    return (f == 0) ? (g + (size_t)i * D)
                    : (p + ((size_t)i * P + (f - 1)) * D);
}

__device__ __forceinline__ unsigned f2bf(float x) {
    unsigned u = __float_as_uint(x);
    return (u + 0x7fffu + ((u >> 16) & 1u)) >> 16;   // RNE
}

// One WAVE per (i,f) row: sum-of-squares via shfl_xor (no barriers),
// scale by label/norm, convert to bf16, store V[(i*F+f)*D + k].
__global__ __launch_bounds__(256)
void pack_kernel(const float* __restrict__ gfeat,
                 const float* __restrict__ pfeat,
                 const float* __restrict__ plab,
                 unsigned short* __restrict__ V) {
    const int wid = (blockIdx.x << 2) | (threadIdx.x >> 6);  // row index i*F+f
    const int lane = threadIdx.x & 63;
    const int i = wid / F, f = wid % F;
    const float* src = feat_row(gfeat, pfeat, i, f);
    const float4* s4 = (const float4*)src;
    float4 a[8];
    #pragma unroll
    for (int q = 0; q < 8; ++q) a[q] = s4[q * 64 + lane];    // coalesced 1KB/q
    float ss = 0.f;
    #pragma unroll
    for (int q = 0; q < 8; ++q)
        ss += a[q].x * a[q].x + a[q].y * a[q].y + a[q].z * a[q].z + a[q].w * a[q].w;
    #pragma unroll
    for (int m = 32; m > 0; m >>= 1) ss += __shfl_xor(ss, m, 64);
    const float ls = (f == 0) ? 1.0f : plab[i * P + (f - 1)];
    const float inv = ls / (sqrtf(ss) + 1e-12f);
    unsigned short* dst = V + (size_t)wid * D;
    #pragma unroll
    for (int q = 0; q < 8; ++q) {
        uint2 o;
        o.x = f2bf(a[q].x * inv) | (f2bf(a[q].y * inv) << 16);
        o.y = f2bf(a[q].z * inv) | (f2bf(a[q].w * inv) << 16);
        *(uint2*)&dst[(q * 64 + lane) * 4] = o;
    }
}

// C = V * V^T, bf16 MFMA, 128x128 tile, runtime split-K (ks = K elems/slice).
// XCD-chunked block swizzle: each XCD owns contiguous z-slices so A/B panels
// (2.4 MB/slice) stay resident in its 4 MB L2.
__global__ __launch_bounds__(256)
void gemm_kernel(const unsigned short* __restrict__ V,
                 float* __restrict__ part, int ks) {
    __shared__ short As[BM * BKT];   // 8 KB, row-major [row][k], 64 B rows
    __shared__ short Bs[BM * BKT];   // 8 KB

    // bijective XCD swizzle (nwg % 8 == 0 for both split=8 and split=16)
    const int nwg = gridDim.x * gridDim.y * gridDim.z;
    const int l = blockIdx.x + gridDim.x * (blockIdx.y + gridDim.y * blockIdx.z);
    const int q = nwg >> 3;
    const int wg = (l & 7) * q + (l >> 3);
    const int bx = wg & 7;           // gridDim.x == 8
    const int rem = wg >> 3;
    const int by = rem & 7;          // gridDim.y == 8
    const int bz = rem >> 3;

    const int t = threadIdx.x;
    const int wave = t >> 6, lane = t & 63;
    const int i0 = by * BM;
    const int j0 = bx * BM;
    const int kbase = bz * ks;
    const int nsteps = ks >> 5;      // ks / BKT

    // staging source: thread t covers tile row t>>2, 16B chunk (t&3)
    const unsigned short* Ap = V + (size_t)(i0 + (t >> 2)) * KTOT + kbase + (t & 3) * 8;
    const unsigned short* Bp = V + (size_t)(j0 + (t >> 2)) * KTOT + kbase + (t & 3) * 8;

    // fragment read bases (LDS, short elems)
    const int kq = lane >> 4;                       // 0..3 -> k = kq*8..kq*8+7
    const short* Abase = As + ((wave & 1) * 64 + (lane & 15)) * BKT + kq * 8;
    const short* Bbase = Bs + ((wave >> 1) * 64 + (lane & 15)) * BKT + kq * 8;

    f32x4 acc[4][4];
    #pragma unroll
    for (int m = 0; m < 4; ++m)
        #pragma unroll
        for (int n = 0; n < 4; ++n)
            acc[m][n] = (f32x4){0.f, 0.f, 0.f, 0.f};

    for (int ksi = 0; ksi < nsteps; ++ksi) {
        __syncthreads();   // previous iteration's readers done
        __builtin_amdgcn_global_load_lds((const GLOBAL_AS void*)Ap,
                                         (LDS_AS void*)(As + t * 8), 16, 0, 0);
        __builtin_amdgcn_global_load_lds((const GLOBAL_AS void*)(Ap + (size_t)64 * KTOT),
                                         (LDS_AS void*)(As + 2048 + t * 8), 16, 0, 0);
        __builtin_amdgcn_global_load_lds((const GLOBAL_AS void*)Bp,
                                         (LDS_AS void*)(Bs + t * 8), 16, 0, 0);
        __builtin_amdgcn_global_load_lds((const GLOBAL_AS void*)(Bp + (size_t)64 * KTOT),
                                         (LDS_AS void*)(Bs + 2048 + t * 8), 16, 0, 0);
        Ap += BKT;
        Bp += BKT;
        __syncthreads();   // staging complete (compiler drains vmcnt before barrier)

        s16x8 af[4], bf[4];
        #pragma unroll
        for (int m = 0; m < 4; ++m) af[m] = *(const s16x8*)(Abase + m * 16 * BKT);
        #pragma unroll
        for (int n = 0; n < 4; ++n) bf[n] = *(const s16x8*)(Bbase + n * 16 * BKT);
        #pragma unroll
        for (int m = 0; m < 4; ++m)
            #pragma unroll
            for (int n = 0; n < 4; ++n)
                acc[m][n] = __builtin_amdgcn_mfma_f32_16x16x32_bf16(
                    af[m], bf[n], acc[m][n], 0, 0, 0);
    }

    // C/D layout: col = lane&15, row = (lane>>4)*4 + reg   [m89-verified]
    float* outp = part + (size_t)bz * N * N;
    const int rbase = i0 + (wave & 1) * 64 + (lane >> 4) * 4;
    const int cbase = j0 + (wave >> 1) * 64 + (lane & 15);
    #pragma unroll
    for (int m = 0; m < 4; ++m)
        #pragma unroll
        for (int n = 0; n < 4; ++n)
            #pragma unroll
            for (int r = 0; r < 4; ++r)
                outp[(size_t)(rbase + m * 16 + r) * N + cbase + n * 16] = acc[m][n][r];
}

// fused: sum split-K partials -> dist -> hardest pos/neg per row
__global__ void mine_kernel(const float* __restrict__ part,
                            const float* __restrict__ plab,
                            const int* __restrict__ glab,
                            float* __restrict__ rowloss, int S) {
    const int i = blockIdx.x;
    const int t = threadIdx.x;
    const int li = glab[i];
    float lab_i[P];
    #pragma unroll
    for (int c = 0; c < P; ++c) lab_i[c] = plab[i * P + c];

    float ap = -1e30f, an = 1e30f;
    for (int j = t; j < N; j += 256) {
        float dot = 0.f;
        for (int s = 0; s < S; ++s)
            dot += part[(size_t)s * N * N + (size_t)i * N + j];
        float ov = 0.f;
        #pragma unroll
        for (int c = 0; c < P; ++c) ov += lab_i[c] * plab[j * P + c];
        float d = 0.5f - dot / (2.0f * (ov + 1.0f));
        if (glab[j] == li) ap = fmaxf(ap, d);
        else               an = fminf(an, d);
    }
    __shared__ float smax[256], smin[256];
    smax[t] = ap; smin[t] = an;
    __syncthreads();
    for (int s = 128; s > 0; s >>= 1) {
        if (t < s) {
            smax[t] = fmaxf(smax[t], smax[t + s]);
            smin[t] = fminf(smin[t], smin[t + s]);
        }
        __syncthreads();
    }
    if (t == 0) rowloss[i] = fmaxf(0.f, smax[0] - smin[0] + MARGIN);
}

__global__ void reduce_kernel(const float* __restrict__ rowloss,
                              float* __restrict__ out) {
    const int t = threadIdx.x;
    float s = rowloss[t] + rowloss[t + 256] + rowloss[t + 512] + rowloss[t + 768];
    __shared__ float red[256];
    red[t] = s;
    __syncthreads();
    for (int st = 128; st > 0; st >>= 1) {
        if (t < st) red[t] += red[t + st];
        __syncthreads();
    }
    if (t == 0) out[0] = red[0] * (1.0f / N);
}

extern "C" void kernel_launch(void* const* d_in, const int* in_sizes, int n_in,
                              void* d_out, int out_size, void* d_ws, size_t ws_size,
                              hipStream_t stream) {
    const float* gfeat = (const float*)d_in[0];
    const float* pfeat = (const float*)d_in[1];
    const float* plab  = (const float*)d_in[2];
    const int*   glab  = (const int*)d_in[3];
    float* out = (float*)d_out;

    const size_t vbytes = (size_t)N * KTOT * 2;     // 37,748,736
    const size_t slice  = (size_t)N * N * 4;        // 4 MB per split slice

    // pick split-K at runtime: 16 slices (4 blocks/CU) only if the workspace
    // provably allows it; otherwise the exact footprint of the passing
    // baseline (8 slices, 71.3 MB).
    int S = (ws_size != 0 && ws_size >= vbytes + 16 * slice + 4096) ? 16 : 8;
    const int ks = KTOT / S;                         // 1152 or 2304

    char* ws = (char*)d_ws;
    unsigned short* V = (unsigned short*)ws;
    float* part    = (float*)(ws + vbytes);
    float* rowloss = (float*)(ws + vbytes + (size_t)S * slice);

    pack_kernel<<<N * F / 4, 256, 0, stream>>>(gfeat, pfeat, plab, V);
    gemm_kernel<<<dim3(N / BM, N / BM, S), 256, 0, stream>>>(V, part, ks);
    mine_kernel<<<N, 256, 0, stream>>>(part, plab, glab, rowloss, S);
    reduce_kernel<<<1, 256, 0, stream>>>(rowloss, out);
}

// Round 3
// 173.348 us; speedup vs baseline: 1.0514x; 1.0514x over previous
//
#include <hip/hip_runtime.h>

#define N 1024
#define D 2048
#define P 8
#define F 9
#define KTOT (F * D)          // 18432
#define BM 128                // tile M = N = 128
#define BKT 32                // K per step (16x16x32 MFMA)
#define MARGIN 0.3f

typedef float f32x4 __attribute__((ext_vector_type(4)));
typedef short s16x8 __attribute__((ext_vector_type(8)));

#define GLOBAL_AS __attribute__((address_space(1)))
#define LDS_AS __attribute__((address_space(3)))

__device__ __forceinline__ const float* feat_row(const float* __restrict__ g,
                                                 const float* __restrict__ p,
                                                 int i, int f) {
    return (f == 0) ? (g + (size_t)i * D)
                    : (p + ((size_t)i * P + (f - 1)) * D);
}

__device__ __forceinline__ unsigned f2bf(float x) {
    unsigned u = __float_as_uint(x);
    return (u + 0x7fffu + ((u >> 16) & 1u)) >> 16;   // RNE
}

// One WAVE per (i,f) row: sum-of-squares via shfl_xor (no barriers),
// scale by label/norm, convert to bf16, store V[(i*F+f)*D + k].
// Lane owns 8 consecutive elems per q (32B loads, 16B stores).
__global__ __launch_bounds__(256)
void pack_kernel(const float* __restrict__ gfeat,
                 const float* __restrict__ pfeat,
                 const float* __restrict__ plab,
                 unsigned short* __restrict__ V) {
    const int wid = (blockIdx.x << 2) | (threadIdx.x >> 6);  // row index i*F+f
    const int lane = threadIdx.x & 63;
    const int i = wid / F, f = wid % F;
    const float* src = feat_row(gfeat, pfeat, i, f);
    const float4* s4 = (const float4*)src;
    float4 a[4][2];
    #pragma unroll
    for (int q = 0; q < 4; ++q) {
        a[q][0] = s4[(q * 64 + lane) * 2];
        a[q][1] = s4[(q * 64 + lane) * 2 + 1];
    }
    float ss = 0.f;
    #pragma unroll
    for (int q = 0; q < 4; ++q)
        #pragma unroll
        for (int h = 0; h < 2; ++h)
            ss += a[q][h].x * a[q][h].x + a[q][h].y * a[q][h].y
                + a[q][h].z * a[q][h].z + a[q][h].w * a[q][h].w;
    #pragma unroll
    for (int m = 32; m > 0; m >>= 1) ss += __shfl_xor(ss, m, 64);
    const float ls = (f == 0) ? 1.0f : plab[i * P + (f - 1)];
    const float inv = ls / (sqrtf(ss) + 1e-12f);
    unsigned short* dst = V + (size_t)wid * D;
    #pragma unroll
    for (int q = 0; q < 4; ++q) {
        uint4 o;
        o.x = f2bf(a[q][0].x * inv) | (f2bf(a[q][0].y * inv) << 16);
        o.y = f2bf(a[q][0].z * inv) | (f2bf(a[q][0].w * inv) << 16);
        o.z = f2bf(a[q][1].x * inv) | (f2bf(a[q][1].y * inv) << 16);
        o.w = f2bf(a[q][1].z * inv) | (f2bf(a[q][1].w * inv) << 16);
        *(uint4*)&dst[(size_t)(q * 64 + lane) * 8] = o;
    }
}

// C = V * V^T, bf16 MFMA, 128x128 tile, runtime split-K (ks = K elems/slice).
// XCD-chunked block swizzle: each XCD owns contiguous z-slices so A/B panels
// (2.4 MB/slice) stay resident in its 4 MB L2.  [verified round 2: FETCH
// 147->18.7 MB]
__global__ __launch_bounds__(256)
void gemm_kernel(const unsigned short* __restrict__ V,
                 float* __restrict__ part, int ks) {
    __shared__ short As[BM * BKT];   // 8 KB, row-major [row][k], 64 B rows
    __shared__ short Bs[BM * BKT];   // 8 KB

    // bijective XCD swizzle (nwg % 8 == 0 for both split=8 and split=16)
    const int nwg = gridDim.x * gridDim.y * gridDim.z;
    const int l = blockIdx.x + gridDim.x * (blockIdx.y + gridDim.y * blockIdx.z);
    const int q = nwg >> 3;
    const int wg = (l & 7) * q + (l >> 3);
    const int bx = wg & 7;           // gridDim.x == 8
    const int rem = wg >> 3;
    const int by = rem & 7;          // gridDim.y == 8
    const int bz = rem >> 3;

    const int t = threadIdx.x;
    const int wave = t >> 6, lane = t & 63;
    const int i0 = by * BM;
    const int j0 = bx * BM;
    const int kbase = bz * ks;
    const int nsteps = ks >> 5;      // ks / BKT

    // staging source: thread t covers tile row t>>2, 16B chunk (t&3)
    const unsigned short* Ap = V + (size_t)(i0 + (t >> 2)) * KTOT + kbase + (t & 3) * 8;
    const unsigned short* Bp = V + (size_t)(j0 + (t >> 2)) * KTOT + kbase + (t & 3) * 8;

    // fragment read bases (LDS, short elems)
    const int kq = lane >> 4;                       // 0..3 -> k = kq*8..kq*8+7
    const short* Abase = As + ((wave & 1) * 64 + (lane & 15)) * BKT + kq * 8;
    const short* Bbase = Bs + ((wave >> 1) * 64 + (lane & 15)) * BKT + kq * 8;

    f32x4 acc[4][4];
    #pragma unroll
    for (int m = 0; m < 4; ++m)
        #pragma unroll
        for (int n = 0; n < 4; ++n)
            acc[m][n] = (f32x4){0.f, 0.f, 0.f, 0.f};

    for (int ksi = 0; ksi < nsteps; ++ksi) {
        __syncthreads();   // previous iteration's readers done
        __builtin_amdgcn_global_load_lds((const GLOBAL_AS void*)Ap,
                                         (LDS_AS void*)(As + t * 8), 16, 0, 0);
        __builtin_amdgcn_global_load_lds((const GLOBAL_AS void*)(Ap + (size_t)64 * KTOT),
                                         (LDS_AS void*)(As + 2048 + t * 8), 16, 0, 0);
        __builtin_amdgcn_global_load_lds((const GLOBAL_AS void*)Bp,
                                         (LDS_AS void*)(Bs + t * 8), 16, 0, 0);
        __builtin_amdgcn_global_load_lds((const GLOBAL_AS void*)(Bp + (size_t)64 * KTOT),
                                         (LDS_AS void*)(Bs + 2048 + t * 8), 16, 0, 0);
        Ap += BKT;
        Bp += BKT;
        __syncthreads();   // staging complete (compiler drains vmcnt before barrier)

        s16x8 af[4], bf[4];
        #pragma unroll
        for (int m = 0; m < 4; ++m) af[m] = *(const s16x8*)(Abase + m * 16 * BKT);
        #pragma unroll
        for (int n = 0; n < 4; ++n) bf[n] = *(const s16x8*)(Bbase + n * 16 * BKT);
        #pragma unroll
        for (int m = 0; m < 4; ++m)
            #pragma unroll
            for (int n = 0; n < 4; ++n)
                acc[m][n] = __builtin_amdgcn_mfma_f32_16x16x32_bf16(
                    af[m], bf[n], acc[m][n], 0, 0, 0);
    }

    // C/D layout: col = lane&15, row = (lane>>4)*4 + reg   [m89-verified]
    float* outp = part + (size_t)bz * N * N;
    const int rbase = i0 + (wave & 1) * 64 + (lane >> 4) * 4;
    const int cbase = j0 + (wave >> 1) * 64 + (lane & 15);
    #pragma unroll
    for (int m = 0; m < 4; ++m)
        #pragma unroll
        for (int n = 0; n < 4; ++n)
            #pragma unroll
            for (int r = 0; r < 4; ++r)
                outp[(size_t)(rbase + m * 16 + r) * N + cbase + n * 16] = acc[m][n][r];
}

// fused: sum split-K partials -> dist -> hardest pos/neg per row.
// S compile-time (fully unrolled), each thread owns 4 consecutive j via
// float4 loads (1 KB/wave-instruction, coalesced); labels straight to regs
// (plab is 32 KB -> cache-resident across blocks); shfl-tree reduction.
template <int S>
__global__ __launch_bounds__(256)
void mine_kernel(const float* __restrict__ part,
                 const float* __restrict__ plab,
                 const int* __restrict__ glab,
                 float* __restrict__ rowloss) {
    const int i = blockIdx.x;
    const int t = threadIdx.x;
    const int wave = t >> 6, lane = t & 63;
    const int j = t * 4;                       // this thread's 4 columns

    // slice-sum: 16 coalesced float4 loads, unrolled
    float4 dot = {0.f, 0.f, 0.f, 0.f};
    #pragma unroll
    for (int s = 0; s < S; ++s) {
        float4 v = *(const float4*)&part[(size_t)s * N * N + (size_t)i * N + j];
        dot.x += v.x; dot.y += v.y; dot.z += v.z; dot.w += v.w;
    }

    // labels for this thread's j-group: 32 contiguous floats (cache-hot)
    float labj[4][8];
    const float4* pj = (const float4*)&plab[(size_t)j * P];
    #pragma unroll
    for (int q = 0; q < 8; ++q) ((float4*)labj)[q] = pj[q];
    int4 gj = *(const int4*)&glab[j];

    const int li = glab[i];
    float lab_i[P];
    #pragma unroll
    for (int c = 0; c < P; ++c) lab_i[c] = plab[i * P + c];

    float ap = -1e30f, an = 1e30f;
    const float dv[4] = {dot.x, dot.y, dot.z, dot.w};
    const int gv[4] = {gj.x, gj.y, gj.z, gj.w};
    #pragma unroll
    for (int u = 0; u < 4; ++u) {
        float ov = 0.f;
        #pragma unroll
        for (int c = 0; c < P; ++c) ov += lab_i[c] * labj[u][c];
        float d = 0.5f - dv[u] / (2.0f * (ov + 1.0f));
        if (gv[u] == li) ap = fmaxf(ap, d);
        else             an = fminf(an, d);
    }

    // wave shfl-tree, then 4-wave LDS combine
    #pragma unroll
    for (int m = 32; m > 0; m >>= 1) {
        ap = fmaxf(ap, __shfl_xor(ap, m, 64));
        an = fminf(an, __shfl_xor(an, m, 64));
    }
    __shared__ float sap[4], san[4];
    if (lane == 0) { sap[wave] = ap; san[wave] = an; }
    __syncthreads();
    if (t == 0) {
        float A = fmaxf(fmaxf(sap[0], sap[1]), fmaxf(sap[2], sap[3]));
        float B = fminf(fminf(san[0], san[1]), fminf(san[2], san[3]));
        rowloss[i] = fmaxf(0.f, A - B + MARGIN);
    }
}

__global__ void reduce_kernel(const float* __restrict__ rowloss,
                              float* __restrict__ out) {
    const int t = threadIdx.x;
    float s = rowloss[t] + rowloss[t + 256] + rowloss[t + 512] + rowloss[t + 768];
    __shared__ float red[256];
    red[t] = s;
    __syncthreads();
    for (int st = 128; st > 0; st >>= 1) {
        if (t < st) red[t] += red[t + st];
        __syncthreads();
    }
    if (t == 0) out[0] = red[0] * (1.0f / N);
}

extern "C" void kernel_launch(void* const* d_in, const int* in_sizes, int n_in,
                              void* d_out, int out_size, void* d_ws, size_t ws_size,
                              hipStream_t stream) {
    const float* gfeat = (const float*)d_in[0];
    const float* pfeat = (const float*)d_in[1];
    const float* plab  = (const float*)d_in[2];
    const int*   glab  = (const int*)d_in[3];
    float* out = (float*)d_out;

    const size_t vbytes = (size_t)N * KTOT * 2;     // 37,748,736
    const size_t slice  = (size_t)N * N * 4;        // 4 MB per split slice

    // split-K: 16 slices (4 blocks/CU) if workspace provably allows, else 8.
    int S = (ws_size != 0 && ws_size >= vbytes + 16 * slice + 4096) ? 16 : 8;
    const int ks = KTOT / S;                         // 1152 or 2304

    char* ws = (char*)d_ws;
    unsigned short* V = (unsigned short*)ws;
    float* part    = (float*)(ws + vbytes);
    float* rowloss = (float*)(ws + vbytes + (size_t)S * slice);

    pack_kernel<<<N * F / 4, 256, 0, stream>>>(gfeat, pfeat, plab, V);
    gemm_kernel<<<dim3(N / BM, N / BM, S), 256, 0, stream>>>(V, part, ks);
    if (S == 16)
        mine_kernel<16><<<N, 256, 0, stream>>>(part, plab, glab, rowloss);
    else
        mine_kernel<8><<<N, 256, 0, stream>>>(part, plab, glab, rowloss);
    reduce_kernel<<<1, 256, 0, stream>>>(rowloss, out);
}

// Round 5
// 168.227 us; speedup vs baseline: 1.0835x; 1.0304x over previous
//
#include <hip/hip_runtime.h>

#define N 1024
#define D 2048
#define P 8
#define F 9
#define KTOT (F * D)          // 18432
#define BM 128                // tile M = N = 128
#define BKT 32                // K per step (16x16x32 MFMA)
#define MARGIN 0.3f

typedef float f32x4 __attribute__((ext_vector_type(4)));
typedef short s16x8 __attribute__((ext_vector_type(8)));

#define GLOBAL_AS __attribute__((address_space(1)))
#define LDS_AS __attribute__((address_space(3)))

__device__ __forceinline__ const float* feat_row(const float* __restrict__ g,
                                                 const float* __restrict__ p,
                                                 int i, int f) {
    return (f == 0) ? (g + (size_t)i * D)
                    : (p + ((size_t)i * P + (f - 1)) * D);
}

__device__ __forceinline__ unsigned f2bf(float x) {
    unsigned u = __float_as_uint(x);
    return (u + 0x7fffu + ((u >> 16) & 1u)) >> 16;   // RNE
}

// One WAVE per (i,f) row: sum-of-squares via shfl_xor (no barriers),
// scale by label/norm, convert to bf16, store V[(i*F+f)*D + k].
// Lane owns 8 consecutive elems per q (32B loads, 16B stores).
__global__ __launch_bounds__(256)
void pack_kernel(const float* __restrict__ gfeat,
                 const float* __restrict__ pfeat,
                 const float* __restrict__ plab,
                 unsigned short* __restrict__ V) {
    const int wid = (blockIdx.x << 2) | (threadIdx.x >> 6);  // row index i*F+f
    const int lane = threadIdx.x & 63;
    const int i = wid / F, f = wid % F;
    const float* src = feat_row(gfeat, pfeat, i, f);
    const float4* s4 = (const float4*)src;
    float4 a[4][2];
    #pragma unroll
    for (int q = 0; q < 4; ++q) {
        a[q][0] = s4[(q * 64 + lane) * 2];
        a[q][1] = s4[(q * 64 + lane) * 2 + 1];
    }
    float ss = 0.f;
    #pragma unroll
    for (int q = 0; q < 4; ++q)
        #pragma unroll
        for (int h = 0; h < 2; ++h)
            ss += a[q][h].x * a[q][h].x + a[q][h].y * a[q][h].y
                + a[q][h].z * a[q][h].z + a[q][h].w * a[q][h].w;
    #pragma unroll
    for (int m = 32; m > 0; m >>= 1) ss += __shfl_xor(ss, m, 64);
    const float ls = (f == 0) ? 1.0f : plab[i * P + (f - 1)];
    const float inv = ls / (sqrtf(ss) + 1e-12f);
    unsigned short* dst = V + (size_t)wid * D;
    #pragma unroll
    for (int q = 0; q < 4; ++q) {
        uint4 o;
        o.x = f2bf(a[q][0].x * inv) | (f2bf(a[q][0].y * inv) << 16);
        o.y = f2bf(a[q][0].z * inv) | (f2bf(a[q][0].w * inv) << 16);
        o.z = f2bf(a[q][1].x * inv) | (f2bf(a[q][1].y * inv) << 16);
        o.w = f2bf(a[q][1].z * inv) | (f2bf(a[q][1].w * inv) << 16);
        *(uint4*)&dst[(size_t)(q * 64 + lane) * 8] = o;
    }
}

// C = V * V^T, bf16 MFMA, 128x128 tile, runtime split-K (ks = K elems/slice).
// SYMMETRY: only the 36 upper-triangle tiles (by<=bx) are computed per slice;
// off-diagonal blocks store both C[i][j] and the mirror C[j][i] (C symmetric,
// partial dots too). Grid per slice 64 -> 36 tiles = 1.78x fewer FLOPs.
// XCD-chunked block swizzle: each XCD owns contiguous z-slices so A/B panels
// stay resident in its 4 MB L2.  [verified round 2: FETCH 147->18.7 MB]
__global__ __launch_bounds__(256)
void gemm_kernel(const unsigned short* __restrict__ V,
                 float* __restrict__ part, int ks) {
    __shared__ short As[BM * BKT];   // 8 KB, row-major [row][k], 64 B rows
    __shared__ short Bs[BM * BKT];   // 8 KB

    // bijective XCD swizzle (nwg = 36*S, divisible by 8 for S=8/16)
    const int nwg = gridDim.x * gridDim.y;
    const int l = blockIdx.x + gridDim.x * blockIdx.y;
    const int q = nwg >> 3;
    const int wg = (l & 7) * q + (l >> 3);
    const int t36 = wg % 36;          // upper-triangle tile index
    const int bz = wg / 36;           // K-slice

    // t36 -> (by, bx) with by <= bx; row by holds (8-by) tiles
    int by = 0, rem = t36;
    while (rem >= 8 - by) { rem -= 8 - by; ++by; }
    const int bx = by + rem;

    const int t = threadIdx.x;
    const int wave = t >> 6, lane = t & 63;
    const int i0 = by * BM;
    const int j0 = bx * BM;
    const int kbase = bz * ks;
    const int nsteps = ks >> 5;      // ks / BKT

    // staging source: thread t covers tile row t>>2, 16B chunk (t&3)
    const unsigned short* Ap = V + (size_t)(i0 + (t >> 2)) * KTOT + kbase + (t & 3) * 8;
    const unsigned short* Bp = V + (size_t)(j0 + (t >> 2)) * KTOT + kbase + (t & 3) * 8;

    // fragment read bases (LDS, short elems)
    const int kq = lane >> 4;                       // 0..3 -> k = kq*8..kq*8+7
    const short* Abase = As + ((wave & 1) * 64 + (lane & 15)) * BKT + kq * 8;
    const short* Bbase = Bs + ((wave >> 1) * 64 + (lane & 15)) * BKT + kq * 8;

    f32x4 acc[4][4];
    #pragma unroll
    for (int m = 0; m < 4; ++m)
        #pragma unroll
        for (int n = 0; n < 4; ++n)
            acc[m][n] = (f32x4){0.f, 0.f, 0.f, 0.f};

    for (int ksi = 0; ksi < nsteps; ++ksi) {
        __syncthreads();   // previous iteration's readers done
        __builtin_amdgcn_global_load_lds((const GLOBAL_AS void*)Ap,
                                         (LDS_AS void*)(As + t * 8), 16, 0, 0);
        __builtin_amdgcn_global_load_lds((const GLOBAL_AS void*)(Ap + (size_t)64 * KTOT),
                                         (LDS_AS void*)(As + 2048 + t * 8), 16, 0, 0);
        __builtin_amdgcn_global_load_lds((const GLOBAL_AS void*)Bp,
                                         (LDS_AS void*)(Bs + t * 8), 16, 0, 0);
        __builtin_amdgcn_global_load_lds((const GLOBAL_AS void*)(Bp + (size_t)64 * KTOT),
                                         (LDS_AS void*)(Bs + 2048 + t * 8), 16, 0, 0);
        Ap += BKT;
        Bp += BKT;
        __syncthreads();   // staging complete (compiler drains vmcnt before barrier)

        s16x8 af[4], bf[4];
        #pragma unroll
        for (int m = 0; m < 4; ++m) af[m] = *(const s16x8*)(Abase + m * 16 * BKT);
        #pragma unroll
        for (int n = 0; n < 4; ++n) bf[n] = *(const s16x8*)(Bbase + n * 16 * BKT);
        #pragma unroll
        for (int m = 0; m < 4; ++m)
            #pragma unroll
            for (int n = 0; n < 4; ++n)
                acc[m][n] = __builtin_amdgcn_mfma_f32_16x16x32_bf16(
                    af[m], bf[n], acc[m][n], 0, 0, 0);
    }

    // C/D layout: col = lane&15, row = (lane>>4)*4 + reg   [m89-verified]
    float* outp = part + (size_t)bz * N * N;
    const int rbase = i0 + (wave & 1) * 64 + (lane >> 4) * 4;
    const int cbase = j0 + (wave >> 1) * 64 + (lane & 15);
    #pragma unroll
    for (int m = 0; m < 4; ++m)
        #pragma unroll
        for (int n = 0; n < 4; ++n)
            #pragma unroll
            for (int r = 0; r < 4; ++r)
                outp[(size_t)(rbase + m * 16 + r) * N + cbase + n * 16] = acc[m][n][r];

    if (bx != by) {
        // mirror write: block collectively covers the full 128x128 transposed
        // region, so L2 write-combining keeps HBM traffic at full-line granularity
        #pragma unroll
        for (int m = 0; m < 4; ++m)
            #pragma unroll
            for (int n = 0; n < 4; ++n)
                #pragma unroll
                for (int r = 0; r < 4; ++r)
                    outp[(size_t)(cbase + n * 16) * N + rbase + m * 16 + r] = acc[m][n][r];
    }
}

// fused: sum split-K partials -> dist -> hardest pos/neg per row.
// S compile-time (fully unrolled), each thread owns 4 consecutive j via
// float4 loads (1 KB/wave-instruction, coalesced); labels straight to regs
// (plab is 32 KB -> cache-resident across blocks); shfl-tree reduction.
template <int S>
__global__ __launch_bounds__(256)
void mine_kernel(const float* __restrict__ part,
                 const float* __restrict__ plab,
                 const int* __restrict__ glab,
                 float* __restrict__ rowloss) {
    const int i = blockIdx.x;
    const int t = threadIdx.x;
    const int wave = t >> 6, lane = t & 63;
    const int j = t * 4;                       // this thread's 4 columns

    // slice-sum: S coalesced float4 loads, unrolled
    float4 dot = {0.f, 0.f, 0.f, 0.f};
    #pragma unroll
    for (int s = 0; s < S; ++s) {
        float4 v = *(const float4*)&part[(size_t)s * N * N + (size_t)i * N + j];
        dot.x += v.x; dot.y += v.y; dot.z += v.z; dot.w += v.w;
    }

    // labels for this thread's j-group: 32 contiguous floats (cache-hot)
    float labj[4][8];
    const float4* pj = (const float4*)&plab[(size_t)j * P];
    #pragma unroll
    for (int q = 0; q < 8; ++q) ((float4*)labj)[q] = pj[q];
    int4 gj = *(const int4*)&glab[j];

    const int li = glab[i];
    float lab_i[P];
    #pragma unroll
    for (int c = 0; c < P; ++c) lab_i[c] = plab[i * P + c];

    float ap = -1e30f, an = 1e30f;
    const float dv[4] = {dot.x, dot.y, dot.z, dot.w};
    const int gv[4] = {gj.x, gj.y, gj.z, gj.w};
    #pragma unroll
    for (int u = 0; u < 4; ++u) {
        float ov = 0.f;
        #pragma unroll
        for (int c = 0; c < P; ++c) ov += lab_i[c] * labj[u][c];
        float d = 0.5f - dv[u] / (2.0f * (ov + 1.0f));
        if (gv[u] == li) ap = fmaxf(ap, d);
        else             an = fminf(an, d);
    }

    // wave shfl-tree, then 4-wave LDS combine
    #pragma unroll
    for (int m = 32; m > 0; m >>= 1) {
        ap = fmaxf(ap, __shfl_xor(ap, m, 64));
        an = fminf(an, __shfl_xor(an, m, 64));
    }
    __shared__ float sap[4], san[4];
    if (lane == 0) { sap[wave] = ap; san[wave] = an; }
    __syncthreads();
    if (t == 0) {
        float A = fmaxf(fmaxf(sap[0], sap[1]), fmaxf(sap[2], sap[3]));
        float B = fminf(fminf(san[0], san[1]), fminf(san[2], san[3]));
        rowloss[i] = fmaxf(0.f, A - B + MARGIN);
    }
}

__global__ void reduce_kernel(const float* __restrict__ rowloss,
                              float* __restrict__ out) {
    const int t = threadIdx.x;
    float s = rowloss[t] + rowloss[t + 256] + rowloss[t + 512] + rowloss[t + 768];
    __shared__ float red[256];
    red[t] = s;
    __syncthreads();
    for (int st = 128; st > 0; st >>= 1) {
        if (t < st) red[t] += red[t + st];
        __syncthreads();
    }
    if (t == 0) out[0] = red[0] * (1.0f / N);
}

extern "C" void kernel_launch(void* const* d_in, const int* in_sizes, int n_in,
                              void* d_out, int out_size, void* d_ws, size_t ws_size,
                              hipStream_t stream) {
    const float* gfeat = (const float*)d_in[0];
    const float* pfeat = (const float*)d_in[1];
    const float* plab  = (const float*)d_in[2];
    const int*   glab  = (const int*)d_in[3];
    float* out = (float*)d_out;

    const size_t vbytes = (size_t)N * KTOT * 2;     // 37,748,736
    const size_t slice  = (size_t)N * N * 4;        // 4 MB per split slice

    // split-K: 16 slices if workspace provably allows, else 8.
    int S = (ws_size != 0 && ws_size >= vbytes + 16 * slice + 4096) ? 16 : 8;
    const int ks = KTOT / S;                         // 1152 or 2304

    char* ws = (char*)d_ws;
    unsigned short* V = (unsigned short*)ws;
    float* part    = (float*)(ws + vbytes);
    float* rowloss = (float*)(ws + vbytes + (size_t)S * slice);

    pack_kernel<<<N * F / 4, 256, 0, stream>>>(gfeat, pfeat, plab, V);
    gemm_kernel<<<dim3(36, S), 256, 0, stream>>>(V, part, ks);
    if (S == 16)
        mine_kernel<16><<<N, 256, 0, stream>>>(part, plab, glab, rowloss);
    else
        mine_kernel<8><<<N, 256, 0, stream>>>(part, plab, glab, rowloss);
    reduce_kernel<<<1, 256, 0, stream>>>(rowloss, out);
}

// Round 6
// 164.391 us; speedup vs baseline: 1.1087x; 1.0233x over previous
//
#include <hip/hip_runtime.h>

#define N 1024
#define D 2048
#define P 8
#define F 9
#define KTOT (F * D)          // 18432
#define BM 128                // tile M = N = 128
#define BKT 32                // K per step (16x16x32 MFMA)
#define MARGIN 0.3f

typedef float f32x4 __attribute__((ext_vector_type(4)));
typedef short s16x8 __attribute__((ext_vector_type(8)));

#define GLOBAL_AS __attribute__((address_space(1)))
#define LDS_AS __attribute__((address_space(3)))

__device__ __forceinline__ const float* feat_row(const float* __restrict__ g,
                                                 const float* __restrict__ p,
                                                 int i, int f) {
    return (f == 0) ? (g + (size_t)i * D)
                    : (p + ((size_t)i * P + (f - 1)) * D);
}

__device__ __forceinline__ unsigned f2bf(float x) {
    unsigned u = __float_as_uint(x);
    return (u + 0x7fffu + ((u >> 16) & 1u)) >> 16;   // RNE
}

// One WAVE per (i,f) row: sum-of-squares via shfl_xor (no barriers),
// scale by label/norm, convert to bf16, store V[(i*F+f)*D + k].
__global__ __launch_bounds__(256)
void pack_kernel(const float* __restrict__ gfeat,
                 const float* __restrict__ pfeat,
                 const float* __restrict__ plab,
                 unsigned short* __restrict__ V) {
    const int wid = (blockIdx.x << 2) | (threadIdx.x >> 6);  // row index i*F+f
    const int lane = threadIdx.x & 63;
    const int i = wid / F, f = wid % F;
    const float* src = feat_row(gfeat, pfeat, i, f);
    const float4* s4 = (const float4*)src;
    float4 a[4][2];
    #pragma unroll
    for (int q = 0; q < 4; ++q) {
        a[q][0] = s4[(q * 64 + lane) * 2];
        a[q][1] = s4[(q * 64 + lane) * 2 + 1];
    }
    float ss = 0.f;
    #pragma unroll
    for (int q = 0; q < 4; ++q)
        #pragma unroll
        for (int h = 0; h < 2; ++h)
            ss += a[q][h].x * a[q][h].x + a[q][h].y * a[q][h].y
                + a[q][h].z * a[q][h].z + a[q][h].w * a[q][h].w;
    #pragma unroll
    for (int m = 32; m > 0; m >>= 1) ss += __shfl_xor(ss, m, 64);
    const float ls = (f == 0) ? 1.0f : plab[i * P + (f - 1)];
    const float inv = ls / (sqrtf(ss) + 1e-12f);
    unsigned short* dst = V + (size_t)wid * D;
    #pragma unroll
    for (int q = 0; q < 4; ++q) {
        uint4 o;
        o.x = f2bf(a[q][0].x * inv) | (f2bf(a[q][0].y * inv) << 16);
        o.y = f2bf(a[q][0].z * inv) | (f2bf(a[q][0].w * inv) << 16);
        o.z = f2bf(a[q][1].x * inv) | (f2bf(a[q][1].y * inv) << 16);
        o.w = f2bf(a[q][1].z * inv) | (f2bf(a[q][1].w * inv) << 16);
        *(uint4*)&dst[(size_t)(q * 64 + lane) * 8] = o;
    }
}

// C = V * V^T, bf16 MFMA, 128x128 tile, runtime split-K.
// SYMMETRY: 36 upper-triangle tiles/slice, mirror-stored (round-5 verified).
// XCD-chunked swizzle (round-2 verified: FETCH 147->18.7 MB).
// NEW: 2-phase double-buffered LDS prefetch (T3 minimum recipe): issue next
// K-step's global_load_lds BEFORE current step's ds_read+MFMA; ONE barrier
// per step. Staging latency (~600-900 cyc, L2/L3-hit) hides under compute.
__global__ __launch_bounds__(256)
void gemm_kernel(const unsigned short* __restrict__ V,
                 float* __restrict__ part, int ks) {
    __shared__ short As[2][BM * BKT];   // 2 x 8 KB
    __shared__ short Bs[2][BM * BKT];   // 2 x 8 KB

    // bijective XCD swizzle (nwg = 36*S, divisible by 8 for S=8/16)
    const int nwg = gridDim.x * gridDim.y;
    const int l = blockIdx.x + gridDim.x * blockIdx.y;
    const int q = nwg >> 3;
    const int wg = (l & 7) * q + (l >> 3);
    const int t36 = wg % 36;          // upper-triangle tile index
    const int bz = wg / 36;           // K-slice

    // t36 -> (by, bx) with by <= bx; row by holds (8-by) tiles
    int by = 0, rem = t36;
    while (rem >= 8 - by) { rem -= 8 - by; ++by; }
    const int bx = by + rem;

    const int t = threadIdx.x;
    const int wave = t >> 6, lane = t & 63;
    const int i0 = by * BM;
    const int j0 = bx * BM;
    const int kbase = bz * ks;
    const int nsteps = ks >> 5;      // ks / BKT: 36 (S=16) or 72 (S=8)

    // staging source: thread t covers tile row t>>2, 16B chunk (t&3)
    const unsigned short* Ap = V + (size_t)(i0 + (t >> 2)) * KTOT + kbase + (t & 3) * 8;
    const unsigned short* Bp = V + (size_t)(j0 + (t >> 2)) * KTOT + kbase + (t & 3) * 8;

    // fragment read offsets (LDS, short elems)
    const int kq = lane >> 4;                       // 0..3 -> k = kq*8..kq*8+7
    const int aoff = ((wave & 1) * 64 + (lane & 15)) * BKT + kq * 8;
    const int boff = ((wave >> 1) * 64 + (lane & 15)) * BKT + kq * 8;

    f32x4 acc[4][4];
    #pragma unroll
    for (int m = 0; m < 4; ++m)
        #pragma unroll
        for (int n = 0; n < 4; ++n)
            acc[m][n] = (f32x4){0.f, 0.f, 0.f, 0.f};

#define STAGE(b) do {                                                          \
    __builtin_amdgcn_global_load_lds((const GLOBAL_AS void*)Ap,                \
        (LDS_AS void*)(&As[(b)][0] + t * 8), 16, 0, 0);                        \
    __builtin_amdgcn_global_load_lds((const GLOBAL_AS void*)(Ap + (size_t)64 * KTOT), \
        (LDS_AS void*)(&As[(b)][2048] + t * 8), 16, 0, 0);                     \
    __builtin_amdgcn_global_load_lds((const GLOBAL_AS void*)Bp,                \
        (LDS_AS void*)(&Bs[(b)][0] + t * 8), 16, 0, 0);                        \
    __builtin_amdgcn_global_load_lds((const GLOBAL_AS void*)(Bp + (size_t)64 * KTOT), \
        (LDS_AS void*)(&Bs[(b)][2048] + t * 8), 16, 0, 0);                     \
    Ap += BKT; Bp += BKT;                                                      \
} while (0)

#define COMPUTE(b) do {                                                        \
    s16x8 af[4], bf[4];                                                        \
    _Pragma("unroll")                                                          \
    for (int m = 0; m < 4; ++m)                                                \
        af[m] = *(const s16x8*)(&As[(b)][aoff + m * 16 * BKT]);                \
    _Pragma("unroll")                                                          \
    for (int n = 0; n < 4; ++n)                                                \
        bf[n] = *(const s16x8*)(&Bs[(b)][boff + n * 16 * BKT]);                \
    _Pragma("unroll")                                                          \
    for (int m = 0; m < 4; ++m)                                                \
        _Pragma("unroll")                                                      \
        for (int n = 0; n < 4; ++n)                                            \
            acc[m][n] = __builtin_amdgcn_mfma_f32_16x16x32_bf16(               \
                af[m], bf[n], acc[m][n], 0, 0, 0);                             \
} while (0)

    // prologue: fill buffer 0
    STAGE(0);
    __syncthreads();                 // drains vmcnt -> buf0 ready

    int cur = 0;
    for (int ksi = 0; ksi < nsteps - 1; ++ksi) {
        STAGE(cur ^ 1);              // issue next tile (no wait)
        COMPUTE(cur);                // ds_read + MFMA on current tile
        __syncthreads();             // drains vmcnt+lgkm -> next buf ready,
                                     // this buf's readers done
        cur ^= 1;
    }
    COMPUTE(cur);                    // epilogue: last tile, no prefetch

#undef STAGE
#undef COMPUTE

    // C/D layout: col = lane&15, row = (lane>>4)*4 + reg   [m89-verified]
    float* outp = part + (size_t)bz * N * N;
    const int rbase = i0 + (wave & 1) * 64 + (lane >> 4) * 4;
    const int cbase = j0 + (wave >> 1) * 64 + (lane & 15);
    #pragma unroll
    for (int m = 0; m < 4; ++m)
        #pragma unroll
        for (int n = 0; n < 4; ++n)
            #pragma unroll
            for (int r = 0; r < 4; ++r)
                outp[(size_t)(rbase + m * 16 + r) * N + cbase + n * 16] = acc[m][n][r];

    if (bx != by) {
        // mirror write: block collectively covers the full 128x128 transposed
        // region; L2 write-combining keeps HBM traffic at full-line granularity
        // [round-5 verified: WRITE_SIZE stayed 65.5 MB]
        #pragma unroll
        for (int m = 0; m < 4; ++m)
            #pragma unroll
            for (int n = 0; n < 4; ++n)
                #pragma unroll
                for (int r = 0; r < 4; ++r)
                    outp[(size_t)(cbase + n * 16) * N + rbase + m * 16 + r] = acc[m][n][r];
    }
}

// fused: sum split-K partials -> dist -> hardest pos/neg per row.
template <int S>
__global__ __launch_bounds__(256)
void mine_kernel(const float* __restrict__ part,
                 const float* __restrict__ plab,
                 const int* __restrict__ glab,
                 float* __restrict__ rowloss) {
    const int i = blockIdx.x;
    const int t = threadIdx.x;
    const int wave = t >> 6, lane = t & 63;
    const int j = t * 4;                       // this thread's 4 columns

    float4 dot = {0.f, 0.f, 0.f, 0.f};
    #pragma unroll
    for (int s = 0; s < S; ++s) {
        float4 v = *(const float4*)&part[(size_t)s * N * N + (size_t)i * N + j];
        dot.x += v.x; dot.y += v.y; dot.z += v.z; dot.w += v.w;
    }

    float labj[4][8];
    const float4* pj = (const float4*)&plab[(size_t)j * P];
    #pragma unroll
    for (int q = 0; q < 8; ++q) ((float4*)labj)[q] = pj[q];
    int4 gj = *(const int4*)&glab[j];

    const int li = glab[i];
    float lab_i[P];
    #pragma unroll
    for (int c = 0; c < P; ++c) lab_i[c] = plab[i * P + c];

    float ap = -1e30f, an = 1e30f;
    const float dv[4] = {dot.x, dot.y, dot.z, dot.w};
    const int gv[4] = {gj.x, gj.y, gj.z, gj.w};
    #pragma unroll
    for (int u = 0; u < 4; ++u) {
        float ov = 0.f;
        #pragma unroll
        for (int c = 0; c < P; ++c) ov += lab_i[c] * labj[u][c];
        float d = 0.5f - dv[u] / (2.0f * (ov + 1.0f));
        if (gv[u] == li) ap = fmaxf(ap, d);
        else             an = fminf(an, d);
    }

    #pragma unroll
    for (int m = 32; m > 0; m >>= 1) {
        ap = fmaxf(ap, __shfl_xor(ap, m, 64));
        an = fminf(an, __shfl_xor(an, m, 64));
    }
    __shared__ float sap[4], san[4];
    if (lane == 0) { sap[wave] = ap; san[wave] = an; }
    __syncthreads();
    if (t == 0) {
        float A = fmaxf(fmaxf(sap[0], sap[1]), fmaxf(sap[2], sap[3]));
        float B = fminf(fminf(san[0], san[1]), fminf(san[2], san[3]));
        rowloss[i] = fmaxf(0.f, A - B + MARGIN);
    }
}

__global__ void reduce_kernel(const float* __restrict__ rowloss,
                              float* __restrict__ out) {
    const int t = threadIdx.x;
    float s = rowloss[t] + rowloss[t + 256] + rowloss[t + 512] + rowloss[t + 768];
    __shared__ float red[256];
    red[t] = s;
    __syncthreads();
    for (int st = 128; st > 0; st >>= 1) {
        if (t < st) red[t] += red[t + st];
        __syncthreads();
    }
    if (t == 0) out[0] = red[0] * (1.0f / N);
}

extern "C" void kernel_launch(void* const* d_in, const int* in_sizes, int n_in,
                              void* d_out, int out_size, void* d_ws, size_t ws_size,
                              hipStream_t stream) {
    const float* gfeat = (const float*)d_in[0];
    const float* pfeat = (const float*)d_in[1];
    const float* plab  = (const float*)d_in[2];
    const int*   glab  = (const int*)d_in[3];
    float* out = (float*)d_out;

    const size_t vbytes = (size_t)N * KTOT * 2;     // 37,748,736
    const size_t slice  = (size_t)N * N * 4;        // 4 MB per split slice

    // split-K: 16 slices if workspace provably allows, else 8.
    int S = (ws_size != 0 && ws_size >= vbytes + 16 * slice + 4096) ? 16 : 8;
    const int ks = KTOT / S;                         // 1152 or 2304

    char* ws = (char*)d_ws;
    unsigned short* V = (unsigned short*)ws;
    float* part    = (float*)(ws + vbytes);
    float* rowloss = (float*)(ws + vbytes + (size_t)S * slice);

    pack_kernel<<<N * F / 4, 256, 0, stream>>>(gfeat, pfeat, plab, V);
    gemm_kernel<<<dim3(36, S), 256, 0, stream>>>(V, part, ks);
    if (S == 16)
        mine_kernel<16><<<N, 256, 0, stream>>>(part, plab, glab, rowloss);
    else
        mine_kernel<8><<<N, 256, 0, stream>>>(part, plab, glab, rowloss);
    reduce_kernel<<<1, 256, 0, stream>>>(rowloss, out);
}